// Round 2
// baseline (1365.082 us; speedup 1.0000x reference)
//
#include <hip/hip_runtime.h>

// RandomPooling2D: out[b,c,i,j] = x[b,c, 2*i + pick_i, 2*j + pick_j]
// B=16, C=64, H=W=512, OH=OW=256, stride=2, kernel=2 (pick_* in {0,1}).
//
// v3: discriminating probe between "kernel is pattern-bound (~600us)" and
// "kernel is ~150us and dur_us is dominated by harness reset poison".
//   - Each lane now reads a CONTIGUOUS 64 B input chunk (4x dwordx4, each
//     load instruction exactly covering full 64 B sectors across the wave)
//     instead of two 16B-at-32B-stride loads (which touched every sector
//     twice at half density). Halves L1/L2 sector request count.
//   - Input loads are nontemporal (pure streaming, zero reuse -> don't
//     allocate in L2). Stores stay cached: L2 write-back merging is what
//     lets the harness fills reach 6.3 TB/s.
//   - Persistent grid kept: 2048 blocks x 256 threads, 16 iterations of
//     8 output floats each.
//
// Layout: W=512 floats/input row (2^9), plane H*W = 2^18, out total 2^26
// floats. Work item n in [0, 2^23): output floats [8n, 8n+8) from input
// floats [16*(n&31), +16) of row 2i+pick_i, i=(n>>5)&255, plane bc=n>>13.
// Grid stride 2^19 touches only bits >=19 of n -> j8, i invariant per
// thread; bc advances by 64 per iteration (input +2^24 floats, out +2^22).

typedef float v4f __attribute__((ext_vector_type(4)));

__global__ __launch_bounds__(256, 8) void RandomPooling2D_kernel(
    const float* __restrict__ x,
    const int* __restrict__ p_pick_i,
    const int* __restrict__ p_pick_j,
    float* __restrict__ out)
{
    const int t = blockIdx.x * blockDim.x + threadIdx.x;   // 0 .. 2^19-1

    const int pick_i = *p_pick_i;   // uniform scalar loads
    const int pick_j = *p_pick_j;

    const int j8  = t & 31;          // which 16-float input / 8-float output chunk
    const int i   = (t >> 5) & 255;  // output row
    const int bc0 = t >> 13;         // starting plane, 0..63

    // 64B-aligned: offset = bc0*2^18 + (2i+pick_i)*2^9 + j8*2^4 floats
    const float* p = x + (((size_t)bc0 << 18)
                        + ((size_t)((i << 1) + pick_i) << 9)
                        + ((size_t)j8 << 4));
    float* q = out + ((size_t)t << 3);   // 8 floats per work item, 32B aligned

    if (pick_j == 0) {               // wave-uniform branch hoisted out of loop
        #pragma unroll 2
        for (int k = 0; k < 16; ++k) {
            const v4f* s = (const v4f*)(p + ((size_t)k << 24));  // +64 planes
            const v4f a0 = __builtin_nontemporal_load(s + 0);
            const v4f a1 = __builtin_nontemporal_load(s + 1);
            const v4f a2 = __builtin_nontemporal_load(s + 2);
            const v4f a3 = __builtin_nontemporal_load(s + 3);
            v4f* d = (v4f*)(q + ((size_t)k << 22));
            d[0] = __builtin_shufflevector(a0, a1, 0, 2, 4, 6);  // even cols
            d[1] = __builtin_shufflevector(a2, a3, 0, 2, 4, 6);
        }
    } else {
        #pragma unroll 2
        for (int k = 0; k < 16; ++k) {
            const v4f* s = (const v4f*)(p + ((size_t)k << 24));
            const v4f a0 = __builtin_nontemporal_load(s + 0);
            const v4f a1 = __builtin_nontemporal_load(s + 1);
            const v4f a2 = __builtin_nontemporal_load(s + 2);
            const v4f a3 = __builtin_nontemporal_load(s + 3);
            v4f* d = (v4f*)(q + ((size_t)k << 22));
            d[0] = __builtin_shufflevector(a0, a1, 1, 3, 5, 7);  // odd cols
            d[1] = __builtin_shufflevector(a2, a3, 1, 3, 5, 7);
        }
    }
}

extern "C" void kernel_launch(void* const* d_in, const int* in_sizes, int n_in,
                              void* d_out, int out_size, void* d_ws, size_t ws_size,
                              hipStream_t stream)
{
    const float* x        = (const float*)d_in[0];
    const int*   p_pick_i = (const int*)d_in[1];
    const int*   p_pick_j = (const int*)d_in[2];
    float*       out      = (float*)d_out;

    // 2^19 threads, 16 x 8-float work items per thread = 2^26 output floats.
    const int block = 256;
    const int grid  = 2048;   // 8 blocks/CU on 256 CUs, fully resident

    RandomPooling2D_kernel<<<grid, block, 0, stream>>>(x, p_pick_i, p_pick_j, out);
}